// Round 10
// baseline (398.529 us; speedup 1.0000x reference)
//
#include <hip/hip_runtime.h>

typedef unsigned short u16;
typedef __attribute__((ext_vector_type(8))) short short8;
typedef __attribute__((ext_vector_type(4))) float f32x4;

#define Bn 4096
#define Vn 20
#define Dn 768
#define Mn (Bn * Vn)   // 81920 rows
#define Nn (2 * Dn)    // 1536 packed m1/m2 columns

#define BM 256
#define BNt 128            // Wt rows per block tile (= 64 output e-columns)
#define HK 32              // K per slice
#define NHK (Dn / HK)      // 24 slices
#define NTILES (Nn / BNt)  // 12 N-tiles
#define GRID ((Mn / BM) * NTILES)   // 320 * 12 = 3840, %8 == 0
#define SLOTU 12288        // u16 per slot: A 256x32 (8192) + B 128x32 (4096)

typedef __attribute__((address_space(1))) void GV;
typedef __attribute__((address_space(3))) void LV;

__device__ __forceinline__ u16 f2bf(float f) {
  union { float f; unsigned u; } v; v.f = f;
  unsigned r = v.u + 0x7FFFu + ((v.u >> 16) & 1u);  // round-to-nearest-even
  return (u16)(r >> 16);
}
__device__ __forceinline__ float bf2f(u16 x) {
  union { unsigned u; float f; } v; v.u = ((unsigned)x) << 16; return v.f;
}

// K-loop LDS map within a rows x 32K u16 region (proven 0-conflict R6-R8):
//   idx = (r>>1)*64 + (r&1)*32 + ((kc ^ ((r>>1)&3))*8) + j
__device__ __forceinline__ int lds_off(int r, int hi) {
  return (r >> 1) * 64 + (r & 1) * 32 + ((hi ^ ((r >> 1) & 3)) * 8);
}
// conv-epilogue LDS map: [c][r] col-major with row-XOR swizzle
__device__ __forceinline__ int fsw(int c, int r) {
  return c * 256 + (r ^ ((c & 31) << 3));
}

// ---------------- kernel 1: row softmax -> bf16 X ----------------
__global__ __launch_bounds__(192) void softmax_k(const float* __restrict__ vf,
                                                 u16* __restrict__ X) {
  size_t row = blockIdx.x;
  const float4* p = (const float4*)(vf + row * Dn);
  int t = threadIdx.x;
  float4 v = p[t];
  float mx = fmaxf(fmaxf(v.x, v.y), fmaxf(v.z, v.w));
  #pragma unroll
  for (int off = 32; off; off >>= 1) mx = fmaxf(mx, __shfl_xor(mx, off));
  __shared__ float rr[3];
  __shared__ float rs[3];
  int wv = t >> 6, ln = t & 63;
  if (!ln) rr[wv] = mx;
  __syncthreads();
  mx = fmaxf(fmaxf(rr[0], rr[1]), rr[2]);
  float e0 = __expf(v.x - mx), e1 = __expf(v.y - mx);
  float e2 = __expf(v.z - mx), e3 = __expf(v.w - mx);
  float s = e0 + e1 + e2 + e3;
  #pragma unroll
  for (int off = 32; off; off >>= 1) s += __shfl_xor(s, off);
  if (!ln) rs[wv] = s;
  __syncthreads();
  float inv = 1.0f / (rs[0] + rs[1] + rs[2]);
  ushort4 o;
  o.x = f2bf(e0 * inv); o.y = f2bf(e1 * inv);
  o.z = f2bf(e2 * inv); o.w = f2bf(e3 * inv);
  ((ushort4*)(X + row * Dn))[t] = o;
}

// ------- kernel 2: pack W1/W2 block-of-32 interleaved, bf16 [1536][768] -----
__global__ __launch_bounds__(256) void build_wt_k(const float* __restrict__ W1,
                                                  const float* __restrict__ W2,
                                                  u16* __restrict__ Wt) {
  int idx = blockIdx.x * 256 + threadIdx.x;
  if (idx >= Dn * Dn) return;
  int j = idx / Dn, d = idx - j * Dn;
  int b = j >> 5, c = j & 31;
  Wt[(size_t)(b * 64 + c) * Dn + d]      = f2bf(W1[(size_t)j * Dn + d]);
  Wt[(size_t)(b * 64 + 32 + c) * Dn + d] = f2bf(W2[(size_t)j * Dn + d]);
}

// -------- kernel 3: GEMM, 2 blocks/CU TLP + fused conv epilogue -------------
// 8 waves (4M x 2N), wave tile 64x64(Wt), acc[4][4]=64 regs, <=128 total
// (launch_bounds(512,4)) so TWO 512-thread blocks co-reside per CU: one
// block's MFMA phase overlaps the other's LDS/stage/barrier phase (m114).
// 24 K-slices of 32; 2-slot ring (48 KiB); per slice: vmcnt(3) -> barrier ->
// 8 ds_read -> lgkm0 -> prio1 16 MFMA prio0 -> barrier -> stage slice+2.
__global__ __launch_bounds__(512, 4) void gemm_fuse_k(
    const u16* __restrict__ X, const u16* __restrict__ Wt,
    const float* __restrict__ b1, const float* __restrict__ b2,
    const float* __restrict__ text, float* __restrict__ out,
    u16* __restrict__ seam,
    const float* __restrict__ cw1, const float* __restrict__ cb1,
    const float* __restrict__ cw2, const float* __restrict__ cb2) {
  __shared__ __align__(16) u16 smem[32768];   // 64 KiB peak (epilogue)

  const int h = blockIdx.x;                      // GRID = 3840, %8==0
  const int lin = (h & 7) * (GRID / 8) + (h >> 3);
  const int by = lin / NTILES, bx = lin - by * NTILES;
  const int brow = by * BM;

  const int t = threadIdx.x, w = t >> 6, l = t & 63;
  const int lo = l & 15, hi = l >> 4;
  const int wrr = w >> 1, wcc = w & 1;           // 4M x 2N

  int offA[4], offB[4];
  #pragma unroll
  for (int m = 0; m < 4; ++m) offA[m] = lds_off(wrr * 64 + m * 16 + lo, hi);
  #pragma unroll
  for (int n = 0; n < 4; ++n) offB[n] = 8192 + lds_off(wcc * 64 + n * 16 + lo, hi);

  // staging sources: thread q fills u16 [q*8..q*8+8) of a region
  const u16* gA[2];
  const u16* gB;
  #pragma unroll
  for (int ii = 0; ii < 2; ++ii) {
    int q = ii * 512 + t;
    int rp = q >> 3, half = (q >> 2) & 1, kc = (q & 3) ^ (rp & 3);
    gA[ii] = X + (size_t)(brow + rp * 2 + half) * Dn + kc * 8;
  }
  {
    int rp = t >> 3, half = (t >> 2) & 1, kc = (t & 3) ^ (rp & 3);
    gB = Wt + (size_t)(bx * BNt + rp * 2 + half) * Dn + kc * 8;
  }

#define STAGE(SLOT, KOFF) do {                                                 \
    _Pragma("unroll")                                                          \
    for (int ii = 0; ii < 2; ++ii)                                             \
      __builtin_amdgcn_global_load_lds((GV*)(gA[ii] + (KOFF)),                 \
          (LV*)(smem + (SLOT) * SLOTU + (ii * 512 + t) * 8), 16, 0, 0);        \
    __builtin_amdgcn_global_load_lds((GV*)(gB + (KOFF)),                       \
        (LV*)(smem + (SLOT) * SLOTU + 8192 + t * 8), 16, 0, 0);                \
  } while (0)

  // prologue: slices 0,1 (6 loads in flight)
  STAGE(0, 0);
  STAGE(1, HK);

  f32x4 acc[4][4] = {};
  short8 af[4], bfr[4];

  #pragma unroll 2
  for (int hk = 0; hk < NHK; ++hk) {
    if (hk < NHK - 2) asm volatile("s_waitcnt vmcnt(3)" ::: "memory");
    else              asm volatile("s_waitcnt vmcnt(0)" ::: "memory");
    __builtin_amdgcn_s_barrier();
    const u16* sa = smem + (hk & 1) * SLOTU;
    #pragma unroll
    for (int m = 0; m < 4; ++m) af[m]  = *(const short8*)(sa + offA[m]);
    #pragma unroll
    for (int n = 0; n < 4; ++n) bfr[n] = *(const short8*)(sa + offB[n]);
    asm volatile("s_waitcnt lgkmcnt(0)" ::: "memory");
    __builtin_amdgcn_sched_barrier(0);
    __builtin_amdgcn_s_setprio(1);
    #pragma unroll
    for (int m = 0; m < 4; ++m)
      #pragma unroll
      for (int n = 0; n < 4; ++n)
        acc[m][n] = __builtin_amdgcn_mfma_f32_16x16x32_bf16(af[m], bfr[n], acc[m][n], 0, 0, 0);
    __builtin_amdgcn_s_setprio(0);
    __builtin_amdgcn_s_barrier();
    if (hk < NHK - 2) STAGE(hk & 1, (hk + 2) * HK);
  }
#undef STAGE

  // ======================= fused-conv epilogue ==============================
  // vmcnt==0, all LDS reads done, barrier passed -> smem reusable.
  const float w10 = cw1[0], w11 = cw1[1], w12 = cw1[2], c1b = cb1[0];
  const float w20 = cw2[0], w21 = cw2[1], w22 = cw2[2], c2b = cb2[0];

  u16* fsm = smem;           // fused [64 c][256 r], swizzled: 32 KiB
  u16* tsm = smem + 16384;   // tmp, same layout: 32 KiB

  // ---- E1: fused -> LDS bf16 (+ seam store for cols 0-3, 60-63) ----
  #pragma unroll
  for (int n = 0; n < 2; ++n) {
    const int cl = wcc * 32 + n * 16 + lo;       // local col 0..63
    const int e  = bx * 64 + cl;
    const float B1 = b1[e], B2 = b2[e];
    #pragma unroll
    for (int m = 0; m < 4; ++m) {
      const int rl = wrr * 64 + m * 16 + hi * 4;
      uint2 pk;
      u16* pku = (u16*)&pk;
      #pragma unroll
      for (int r = 0; r < 4; ++r) {
        const int gr = brow + rl + r;
        const float v1 = acc[m][n][r] + B1;
        const float v2 = acc[m][n + 2][r] + B2;
        const float tf = text[(size_t)(gr / Vn) * Dn + e];
        pku[r] = f2bf(fmaxf(tf * v1 + v2, 0.0f));
      }
      *(uint2*)(fsm + fsw(cl, rl)) = pk;
      const int sidx = (cl < 4) ? cl : ((cl >= 60) ? cl - 56 : -1);
      if (sidx >= 0)
        *(uint2*)(seam + ((size_t)(by * NTILES + bx) * 8 + sidx) * 256 + rl) = pk;
    }
  }
  __syncthreads();

  // ---- E2: tmp = relu(conv1(fused)); own col kept in regs ----
  const int cl = t & 63, rb = t >> 6;            // 8 row-groups of 32
  const int cL = cl ? cl - 1 : 0, cR = (cl < 63) ? cl + 1 : 63;
  short8 tC[4];
  #pragma unroll
  for (int j = 0; j < 4; ++j) {
    const int R = rb * 32 + j * 8;
    short8 sL = *(const short8*)(fsm + fsw(cL, R));
    short8 sC = *(const short8*)(fsm + fsw(cl, R));
    short8 sR = *(const short8*)(fsm + fsw(cR, R));
    short8 o;
    #pragma unroll
    for (int k = 0; k < 8; ++k) {
      float a = bf2f((u16)sL[k]), b = bf2f((u16)sC[k]), c = bf2f((u16)sR[k]);
      o[k] = (short)f2bf(fmaxf(fmaf(w10, a, fmaf(w11, b, fmaf(w12, c, c1b))), 0.0f));
    }
    *(short8*)(tsm + fsw(cl, R)) = o;
    tC[j] = o;
  }
  __syncthreads();

  // ---- E3: out = conv2(tmp), store interior cols 2..61 ----
  const bool wr_ok = (cl >= 2 && cl <= 61);
  #pragma unroll
  for (int j = 0; j < 4; ++j) {
    const int R = rb * 32 + j * 8;
    short8 tL = *(const short8*)(tsm + fsw(cL, R));
    short8 tR = *(const short8*)(tsm + fsw(cR, R));
    #pragma unroll
    for (int k = 0; k < 8; ++k) {
      float v = fmaf(w20, bf2f((u16)tL[k]),
                fmaf(w21, bf2f((u16)tC[j][k]),
                fmaf(w22, bf2f((u16)tR[k]), c2b)));
      if (wr_ok)
        out[(size_t)(brow + R + k) * Dn + bx * 64 + cl] = v;
    }
  }
}

// ------- kernel 4: seam cleanup — out cols {E0,E0+1,E0+62,E0+63} -----------
// Zero-pad semantics: conv2 pad -> tmp(-1)=tmp(768)=0; conv1 pad ->
// fused(-1)=fused(768)=0 inside tmp(0)/tmp(767).
__global__ __launch_bounds__(256) void seam_k(const u16* __restrict__ seam,
                                              float* __restrict__ out,
                                              const float* __restrict__ cw1,
                                              const float* __restrict__ cb1,
                                              const float* __restrict__ cw2,
                                              const float* __restrict__ cb2) {
  const int bid = blockIdx.x;          // by*12+bx
  const int by = bid / NTILES, bx = bid - by * NTILES;
  const int r = threadIdx.x;
  const float w10 = cw1[0], w11 = cw1[1], w12 = cw1[2], c1b = cb1[0];
  const float w20 = cw2[0], w21 = cw2[1], w22 = cw2[2], c2b = cb2[0];
  #define SM(B, I) bf2f(seam[((size_t)(B) * 8 + (I)) * 256 + r])
  float fm2 = 0.f, fm1 = 0.f, fR0 = 0.f, fR1 = 0.f;
  if (bx > 0)          { fm2 = SM(bid - 1, 6); fm1 = SM(bid - 1, 7); }
  if (bx < NTILES - 1) { fR0 = SM(bid + 1, 0); fR1 = SM(bid + 1, 1); }
  const float f0 = SM(bid, 0), f1 = SM(bid, 1), f2 = SM(bid, 2), f3 = SM(bid, 3);
  const float f60 = SM(bid, 4), f61 = SM(bid, 5), f62 = SM(bid, 6), f63 = SM(bid, 7);
  #undef SM
  #define C1(a, b, c) fmaxf(fmaf(w10, (a), fmaf(w11, (b), fmaf(w12, (c), c1b))), 0.0f)
  const float tm1 = (bx > 0) ? C1(fm2, fm1, f0) : 0.0f;              // tmp(-1)=0 at edge
  const float t0  = C1(fm1, f0, f1);
  const float t1  = C1(f0, f1, f2);
  const float t2  = C1(f1, f2, f3);
  const float t61 = C1(f60, f61, f62);
  const float t62 = C1(f61, f62, f63);
  const float t63 = C1(f62, f63, fR0);
  const float t64 = (bx < NTILES - 1) ? C1(f63, fR0, fR1) : 0.0f;    // tmp(768)=0 at edge
  #undef C1
  const size_t go = (size_t)(by * 256 + r) * Dn + bx * 64;
  out[go + 0]  = fmaf(w20, tm1, fmaf(w21, t0,  fmaf(w22, t1,  c2b)));
  out[go + 1]  = fmaf(w20, t0,  fmaf(w21, t1,  fmaf(w22, t2,  c2b)));
  out[go + 62] = fmaf(w20, t61, fmaf(w21, t62, fmaf(w22, t63, c2b)));
  out[go + 63] = fmaf(w20, t62, fmaf(w21, t63, fmaf(w22, t64, c2b)));
}

extern "C" void kernel_launch(void* const* d_in, const int* in_sizes, int n_in,
                              void* d_out, int out_size, void* d_ws, size_t ws_size,
                              hipStream_t stream) {
  const float* text = (const float*)d_in[0];
  const float* vf   = (const float*)d_in[1];
  const float* W1   = (const float*)d_in[2];
  const float* b1   = (const float*)d_in[3];
  const float* W2   = (const float*)d_in[4];
  const float* b2   = (const float*)d_in[5];
  const float* cw1  = (const float*)d_in[6];
  const float* cb1  = (const float*)d_in[7];
  const float* cw2  = (const float*)d_in[8];
  const float* cb2  = (const float*)d_in[9];
  float* out = (float*)d_out;

  u16* X    = (u16*)d_ws;                        // [81920][768] bf16
  u16* Wt   = X + (size_t)Mn * Dn;               // [1536][768] bf16
  u16* seam = Wt + (size_t)Nn * Dn;              // [3840][8][256] bf16 (15.7 MB)

  softmax_k<<<Mn, 192, 0, stream>>>(vf, X);
  build_wt_k<<<(Dn * Dn + 255) / 256, 256, 0, stream>>>(W1, W2, Wt);
  gemm_fuse_k<<<GRID, 512, 0, stream>>>(X, Wt, b1, b2, text, out, seam,
                                        cw1, cb1, cw2, cb2);
  seam_k<<<GRID, 256, 0, stream>>>(seam, out, cw1, cb1, cw2, cb2);
}